// Round 4
// baseline (163.350 us; speedup 1.0000x reference)
//
#include <hip/hip_runtime.h>

// B=8, N=16384, E=64, F=64. Positions = B*N = 131072.
// Y[f, (p,i)] = sum_{k=0..191} Mcat[f][k] * T[p][k][i];  Mcat = [A|Bw|C].
// MFMA GEMM (16x16x32 f16), single-buffer LDS (18.4 KB -> 8 blocks/CU),
// register prefetch of J/X across the whole iteration, 2 barriers/iter.

#define NPOS   131072
#define PB     16            // positions per block-iteration
#define NC     (PB * 3)      // 48 N-columns per iteration
#define ITERS  4
#define BLOCKS 2048          // 2048 * 4 * 16 = 131072
#define THREADS 256          // 4 waves; wave w owns f-tile [16w,16w+16)
#define PPW    4             // positions per wave per iteration

typedef _Float16 half8 __attribute__((ext_vector_type(8)));
typedef float floatx4 __attribute__((ext_vector_type(4)));

__global__ __launch_bounds__(THREADS, 8)
void fused_mfma(const float* __restrict__ X, const float* __restrict__ J,
                const float* __restrict__ A, const float* __restrict__ Bw,
                const float* __restrict__ Cm, float* __restrict__ Y) {
    // Fragment-ordered term buffer: kappa = ks*32 + kg*8 + j.
    // Physical kg slot is XOR-swizzled by ((n>>1)&3) so the P2 b128 read
    // (16 n-columns x 4 kg-groups) spreads over all 8 4-bank groups
    // (2 lanes/group = free), instead of 8-way conflicts.
    __shared__ _Float16 Tl[6][NC][4][8];   // 18432 B -> 8 blocks/CU

    const int lane = threadIdx.x & 63;
    const int w    = threadIdx.x >> 6;

    // ---- Mcat fragments in registers for the whole kernel.
    // lane holds Mcat[f = 16w+(l&15)][k = ks*32 + (l>>4)*8 + j], j=0..7.
    const int fa  = w * 16 + (lane & 15);
    const int kgA = lane >> 4;
    half8 afrag[6];
    #pragma unroll
    for (int ks = 0; ks < 6; ++ks) {
        const float* mat = (ks < 2) ? A : (ks < 4 ? Bw : Cm);
        const float* src = mat + fa * 64 + (ks & 1) * 32 + kgA * 8;
        float4 lo = *(const float4*)src;
        float4 hi = *(const float4*)(src + 4);
        half8 h;
        h[0] = (_Float16)lo.x; h[1] = (_Float16)lo.y;
        h[2] = (_Float16)lo.z; h[3] = (_Float16)lo.w;
        h[4] = (_Float16)hi.x; h[5] = (_Float16)hi.y;
        h[6] = (_Float16)hi.z; h[7] = (_Float16)hi.w;
        afrag[ks] = h;
    }

    // Phase-1 write coords (e = lane): ks = 2t + (e>>5), kg = (e&31)>>3, j = e&7.
    const int ks0 = lane >> 5;
    const int kgW = (lane & 31) >> 3;
    const int jW  = lane & 7;
    // Phase-2 read kg slot for this lane (nt-independent since nt*8 % 4 == 0).
    const int kgR = (lane >> 4) ^ (((lane & 15) >> 1) & 3);

    float jr[PPW][3], xr[PPW][3];   // prefetch registers (static-indexed)

    auto LOAD = [&](int it) {
        #pragma unroll
        for (int q = 0; q < PPW; ++q) {
            const int p = (blockIdx.x * ITERS + it) * PB + w * PPW + q;
            const float* jp = J + (size_t)(p * 64 + lane) * 3;
            const float* xp = X + (size_t)(p * 64 + lane) * 3;
            jr[q][0] = jp[0]; jr[q][1] = jp[1]; jr[q][2] = jp[2];
            xr[q][0] = xp[0]; xr[q][1] = xp[1]; xr[q][2] = xp[2];
        }
    };

    auto P1 = [&]() {
        #pragma unroll
        for (int q = 0; q < PPW; ++q) {
            const int p_local = w * PPW + q;
            float ja = jr[q][0], jb = jr[q][1], jg = jr[q][2];
            float x0 = xr[q][0], x1 = xr[q][1], x2 = xr[q][2];
            float sa, ca, sb, cb, sg, cg;
            __sincosf(ja, &sa, &ca);
            __sincosf(jb, &sb, &cb);
            __sincosf(jg, &sg, &cg);
            float casb = ca * sb, sasb = sa * sb;
            float r00 = ca * cb, r01 = casb * sg - sa * cg, r02 = casb * cg + sa * sg;
            float r10 = sa * cb, r11 = sasb * sg + ca * cg, r12 = sasb * cg - ca * sg;
            float r20 = -sb,     r21 = cb * sg,             r22 = cb * cg;
            float v0 = fmaf(r00, x0, fmaf(r10, x1, r20 * x2));
            float v1 = fmaf(r01, x0, fmaf(r11, x1, r21 * x2));
            float v2 = fmaf(r02, x0, fmaf(r12, x1, r22 * x2));
            float ta[3], tb[3], tc[3];
            ta[0] = fmaf(r00, v0, r01 * v1);
            ta[1] = fmaf(r10, v0, r11 * v1);
            ta[2] = fmaf(r20, v0, r21 * v1);
            tb[0] = fmaf(r01, v0, -r00 * v1);
            tb[1] = fmaf(r11, v0, -r10 * v1);
            tb[2] = fmaf(r21, v0, -r20 * v1);
            tc[0] = r02 * v2; tc[1] = r12 * v2; tc[2] = r22 * v2;

            #pragma unroll
            for (int i = 0; i < 3; ++i) {
                const int n  = p_local * 3 + i;
                const int kg = kgW ^ ((n >> 1) & 3);    // swizzled slot
                Tl[0 + ks0][n][kg][jW] = (_Float16)ta[i];
                Tl[2 + ks0][n][kg][jW] = (_Float16)tb[i];
                Tl[4 + ks0][n][kg][jW] = (_Float16)tc[i];
            }
        }
    };

    auto P2 = [&](int it) {
        #pragma unroll
        for (int nt = 0; nt < 3; ++nt) {
            floatx4 acc = {0.f, 0.f, 0.f, 0.f};
            #pragma unroll
            for (int ks = 0; ks < 6; ++ks) {
                half8 b = *(const half8*)&Tl[ks][nt * 16 + (lane & 15)][kgR][0];
                acc = __builtin_amdgcn_mfma_f32_16x16x32_f16(afrag[ks], b, acc, 0, 0, 0);
            }
            const int n = nt * 16 + (lane & 15);
            const int pl2 = (n * 171) >> 9;      // n/3 for n < 96
            const int i2  = n - pl2 * 3;
            const int p2  = (blockIdx.x * ITERS + it) * PB + pl2;
            float* yp = Y + (size_t)p2 * 192 + i2;
            const int fbase = w * 16 + (lane >> 4) * 4;
            #pragma unroll
            for (int r = 0; r < 4; ++r)
                __builtin_nontemporal_store(acc[r], &yp[(fbase + r) * 3]);
        }
    };

    // ---- Pipeline: single LDS buffer, loads prefetched a full iter ahead.
    LOAD(0);
    P1();
    for (int t = 0; t < ITERS; ++t) {
        __syncthreads();                   // Tl writes visible to all waves
        if (t + 1 < ITERS) LOAD(t + 1);    // issue prefetch; consumed in next P1
        P2(t);
        if (t + 1 < ITERS) {
            __syncthreads();               // all waves done reading Tl
            P1();                          // overwrite Tl for t+1
        }
    }
}

extern "C" void kernel_launch(void* const* d_in, const int* in_sizes, int n_in,
                              void* d_out, int out_size, void* d_ws, size_t ws_size,
                              hipStream_t stream) {
    const float* X  = (const float*)d_in[0];
    const float* J  = (const float*)d_in[1];
    const float* A  = (const float*)d_in[2];
    const float* Bw = (const float*)d_in[3];
    const float* Cm = (const float*)d_in[4];
    float* Y = (float*)d_out;
    fused_mfma<<<BLOCKS, THREADS, 0, stream>>>(X, J, A, Bw, Cm, Y);
}

// Round 5
// 97.648 us; speedup vs baseline: 1.6728x; 1.6728x over previous
//
#include <hip/hip_runtime.h>

// B=8, N=16384, E=64, F=64. Positions = B*N = 131072.
// Y[f, (p,i)] = sum_{k=0..191} Mcat[f][k] * T[p][k][i];  Mcat = [A|Bw|C].
// MFMA GEMM (16x16x32 f16), single-buffer LDS (18.4 KB -> 8 blocks/CU),
// register prefetch of J/X across the whole iteration, 2 barriers/iter.
// launch_bounds min-waves=4: R4's min-waves=8 forced VGPR 60->32 and
// spilled the prefetch regs to scratch (+270 MB writes). Keep 4.

#define NPOS   131072
#define PB     16            // positions per block-iteration
#define NC     (PB * 3)      // 48 N-columns per iteration
#define ITERS  4
#define BLOCKS 2048          // 2048 * 4 * 16 = 131072
#define THREADS 256          // 4 waves; wave w owns f-tile [16w,16w+16)
#define PPW    4             // positions per wave per iteration

typedef _Float16 half8 __attribute__((ext_vector_type(8)));
typedef float floatx4 __attribute__((ext_vector_type(4)));

__global__ __launch_bounds__(THREADS, 4)
void fused_mfma(const float* __restrict__ X, const float* __restrict__ J,
                const float* __restrict__ A, const float* __restrict__ Bw,
                const float* __restrict__ Cm, float* __restrict__ Y) {
    // Fragment-ordered term buffer: kappa = ks*32 + kg*8 + j.
    // Physical kg slot XOR-swizzled by ((n>>1)&3): P2 b128 reads spread
    // 2 lanes/4-bank-group (free); P1 writes stay bijective per chunk.
    __shared__ _Float16 Tl[6][NC][4][8];   // 18432 B -> 8 blocks/CU

    const int lane = threadIdx.x & 63;
    const int w    = threadIdx.x >> 6;

    // ---- Mcat fragments in registers for the whole kernel.
    // lane holds Mcat[f = 16w+(l&15)][k = ks*32 + (l>>4)*8 + j], j=0..7.
    const int fa  = w * 16 + (lane & 15);
    const int kgA = lane >> 4;
    half8 afrag[6];
    #pragma unroll
    for (int ks = 0; ks < 6; ++ks) {
        const float* mat = (ks < 2) ? A : (ks < 4 ? Bw : Cm);
        const float* src = mat + fa * 64 + (ks & 1) * 32 + kgA * 8;
        float4 lo = *(const float4*)src;
        float4 hi = *(const float4*)(src + 4);
        half8 h;
        h[0] = (_Float16)lo.x; h[1] = (_Float16)lo.y;
        h[2] = (_Float16)lo.z; h[3] = (_Float16)lo.w;
        h[4] = (_Float16)hi.x; h[5] = (_Float16)hi.y;
        h[6] = (_Float16)hi.z; h[7] = (_Float16)hi.w;
        afrag[ks] = h;
    }

    // Phase-1 write coords (e = lane): ks = 2t + (e>>5), kg = (e&31)>>3, j = e&7.
    const int ks0 = lane >> 5;
    const int kgW = (lane & 31) >> 3;
    const int jW  = lane & 7;
    // Phase-2 read kg slot (nt-independent since nt*16 % 4 == 0).
    const int kgR = (lane >> 4) ^ (((lane & 15) >> 1) & 3);

    float jr[PPW][3], xr[PPW][3];   // prefetch registers (static-indexed)

    auto LOAD = [&](int it) {
        #pragma unroll
        for (int q = 0; q < PPW; ++q) {
            const int p = (blockIdx.x * ITERS + it) * PB + w * PPW + q;
            const float* jp = J + (size_t)(p * 64 + lane) * 3;
            const float* xp = X + (size_t)(p * 64 + lane) * 3;
            jr[q][0] = jp[0]; jr[q][1] = jp[1]; jr[q][2] = jp[2];
            xr[q][0] = xp[0]; xr[q][1] = xp[1]; xr[q][2] = xp[2];
        }
    };

    auto P1 = [&]() {
        #pragma unroll
        for (int q = 0; q < PPW; ++q) {
            const int p_local = w * PPW + q;
            float ja = jr[q][0], jb = jr[q][1], jg = jr[q][2];
            float x0 = xr[q][0], x1 = xr[q][1], x2 = xr[q][2];
            float sa, ca, sb, cb, sg, cg;
            __sincosf(ja, &sa, &ca);
            __sincosf(jb, &sb, &cb);
            __sincosf(jg, &sg, &cg);
            float casb = ca * sb, sasb = sa * sb;
            float r00 = ca * cb, r01 = casb * sg - sa * cg, r02 = casb * cg + sa * sg;
            float r10 = sa * cb, r11 = sasb * sg + ca * cg, r12 = sasb * cg - ca * sg;
            float r20 = -sb,     r21 = cb * sg,             r22 = cb * cg;
            float v0 = fmaf(r00, x0, fmaf(r10, x1, r20 * x2));
            float v1 = fmaf(r01, x0, fmaf(r11, x1, r21 * x2));
            float v2 = fmaf(r02, x0, fmaf(r12, x1, r22 * x2));
            float ta[3], tb[3], tc[3];
            ta[0] = fmaf(r00, v0, r01 * v1);
            ta[1] = fmaf(r10, v0, r11 * v1);
            ta[2] = fmaf(r20, v0, r21 * v1);
            tb[0] = fmaf(r01, v0, -r00 * v1);
            tb[1] = fmaf(r11, v0, -r10 * v1);
            tb[2] = fmaf(r21, v0, -r20 * v1);
            tc[0] = r02 * v2; tc[1] = r12 * v2; tc[2] = r22 * v2;

            #pragma unroll
            for (int i = 0; i < 3; ++i) {
                const int n  = p_local * 3 + i;
                const int kg = kgW ^ ((n >> 1) & 3);    // swizzled slot
                Tl[0 + ks0][n][kg][jW] = (_Float16)ta[i];
                Tl[2 + ks0][n][kg][jW] = (_Float16)tb[i];
                Tl[4 + ks0][n][kg][jW] = (_Float16)tc[i];
            }
        }
    };

    auto P2 = [&](int it) {
        #pragma unroll
        for (int nt = 0; nt < 3; ++nt) {
            floatx4 acc = {0.f, 0.f, 0.f, 0.f};
            #pragma unroll
            for (int ks = 0; ks < 6; ++ks) {
                half8 b = *(const half8*)&Tl[ks][nt * 16 + (lane & 15)][kgR][0];
                acc = __builtin_amdgcn_mfma_f32_16x16x32_f16(afrag[ks], b, acc, 0, 0, 0);
            }
            const int n = nt * 16 + (lane & 15);
            const int pl2 = (n * 171) >> 9;      // n/3 for n < 96
            const int i2  = n - pl2 * 3;
            const int p2  = (blockIdx.x * ITERS + it) * PB + pl2;
            float* yp = Y + (size_t)p2 * 192 + i2;
            const int fbase = w * 16 + (lane >> 4) * 4;
            #pragma unroll
            for (int r = 0; r < 4; ++r)
                __builtin_nontemporal_store(acc[r], &yp[(fbase + r) * 3]);
        }
    };

    // ---- Pipeline: single LDS buffer, loads prefetched a full iter ahead.
    LOAD(0);
    P1();
    for (int t = 0; t < ITERS; ++t) {
        __syncthreads();                   // Tl writes visible to all waves
        if (t + 1 < ITERS) LOAD(t + 1);    // issue prefetch; consumed in next P1
        P2(t);
        if (t + 1 < ITERS) {
            __syncthreads();               // all waves done reading Tl
            P1();                          // overwrite Tl for t+1
        }
    }
}

extern "C" void kernel_launch(void* const* d_in, const int* in_sizes, int n_in,
                              void* d_out, int out_size, void* d_ws, size_t ws_size,
                              hipStream_t stream) {
    const float* X  = (const float*)d_in[0];
    const float* J  = (const float*)d_in[1];
    const float* A  = (const float*)d_in[2];
    const float* Bw = (const float*)d_in[3];
    const float* Cm = (const float*)d_in[4];
    float* Y = (float*)d_out;
    fused_mfma<<<BLOCKS, THREADS, 0, stream>>>(X, J, A, Bw, Cm, Y);
}

// Round 6
// 56.144 us; speedup vs baseline: 2.9095x; 1.7392x over previous
//
#include <hip/hip_runtime.h>

// B=8, N=16384, E=64, F=64. Positions = B*N = 131072.
// Y[f, (p,i)] = sum_{k=0..191} Mcat[f][k] * T[p][k][i];  Mcat = [A|Bw|C].
// MFMA GEMM (16x16x32 f16), single-buffer term LDS + separate Y-staging LDS.
// R5 lesson: scattered 4B nt stores caused 2.1x write amplification
// (WRITE_SIZE 210MB vs 100.6MB output). Epilogue now stages acc in LDS and
// issues contiguous float4 stores (full 64B lines).

#define NPOS   131072
#define PB     16            // positions per block-iteration
#define NC     (PB * 3)      // 48 N-columns per iteration
#define ITERS  4
#define BLOCKS 2048          // 2048 * 4 * 16 = 131072
#define THREADS 256          // 4 waves; wave w owns f-tile [16w,16w+16)
#define PPW    4             // positions per wave per iteration

typedef _Float16 half8 __attribute__((ext_vector_type(8)));
typedef float floatx4 __attribute__((ext_vector_type(4)));

__global__ __launch_bounds__(THREADS, 4)
void fused_mfma(const float* __restrict__ X, const float* __restrict__ J,
                const float* __restrict__ A, const float* __restrict__ Bw,
                const float* __restrict__ Cm, float* __restrict__ Y) {
    // Terms: kappa = ks*32 + kg*8 + j, kg slot XOR-swizzled by ((n>>1)&3)
    // (R4 verified: bank conflicts 2.36M -> 0).
    __shared__ _Float16 Tl[6][NC][4][8];     // 18432 B
    // Y staging: identical layout to the block's contiguous Y slice
    // (PB*192 floats = 12288 B). Scattered 4B writes, coalesced b128 reads.
    __shared__ float Ys[PB * 192];           // 12288 B   (total 30720 B)

    const int lane = threadIdx.x & 63;
    const int w    = threadIdx.x >> 6;
    const int tid  = threadIdx.x;

    // ---- Mcat fragments in registers for the whole kernel.
    // lane holds Mcat[f = 16w+(l&15)][k = ks*32 + (l>>4)*8 + j], j=0..7.
    const int fa  = w * 16 + (lane & 15);
    const int kgA = lane >> 4;
    half8 afrag[6];
    #pragma unroll
    for (int ks = 0; ks < 6; ++ks) {
        const float* mat = (ks < 2) ? A : (ks < 4 ? Bw : Cm);
        const float* src = mat + fa * 64 + (ks & 1) * 32 + kgA * 8;
        float4 lo = *(const float4*)src;
        float4 hi = *(const float4*)(src + 4);
        half8 h;
        h[0] = (_Float16)lo.x; h[1] = (_Float16)lo.y;
        h[2] = (_Float16)lo.z; h[3] = (_Float16)lo.w;
        h[4] = (_Float16)hi.x; h[5] = (_Float16)hi.y;
        h[6] = (_Float16)hi.z; h[7] = (_Float16)hi.w;
        afrag[ks] = h;
    }

    // Phase-1 write coords (e = lane): ks = 2t + (e>>5), kg = (e&31)>>3, j = e&7.
    const int ks0 = lane >> 5;
    const int kgW = (lane & 31) >> 3;
    const int jW  = lane & 7;
    // Phase-2 read kg slot (nt-independent since nt*16 % 4 == 0).
    const int kgR = (lane >> 4) ^ (((lane & 15) >> 1) & 3);

    float jr[PPW][3], xr[PPW][3];   // prefetch registers (static-indexed)

    auto LOAD = [&](int it) {
        #pragma unroll
        for (int q = 0; q < PPW; ++q) {
            const int p = (blockIdx.x * ITERS + it) * PB + w * PPW + q;
            const float* jp = J + (size_t)(p * 64 + lane) * 3;
            const float* xp = X + (size_t)(p * 64 + lane) * 3;
            jr[q][0] = jp[0]; jr[q][1] = jp[1]; jr[q][2] = jp[2];
            xr[q][0] = xp[0]; xr[q][1] = xp[1]; xr[q][2] = xp[2];
        }
    };

    auto P1 = [&]() {
        #pragma unroll
        for (int q = 0; q < PPW; ++q) {
            const int p_local = w * PPW + q;
            float ja = jr[q][0], jb = jr[q][1], jg = jr[q][2];
            float x0 = xr[q][0], x1 = xr[q][1], x2 = xr[q][2];
            float sa, ca, sb, cb, sg, cg;
            __sincosf(ja, &sa, &ca);
            __sincosf(jb, &sb, &cb);
            __sincosf(jg, &sg, &cg);
            float casb = ca * sb, sasb = sa * sb;
            float r00 = ca * cb, r01 = casb * sg - sa * cg, r02 = casb * cg + sa * sg;
            float r10 = sa * cb, r11 = sasb * sg + ca * cg, r12 = sasb * cg - ca * sg;
            float r20 = -sb,     r21 = cb * sg,             r22 = cb * cg;
            float v0 = fmaf(r00, x0, fmaf(r10, x1, r20 * x2));
            float v1 = fmaf(r01, x0, fmaf(r11, x1, r21 * x2));
            float v2 = fmaf(r02, x0, fmaf(r12, x1, r22 * x2));
            float ta[3], tb[3], tc[3];
            ta[0] = fmaf(r00, v0, r01 * v1);
            ta[1] = fmaf(r10, v0, r11 * v1);
            ta[2] = fmaf(r20, v0, r21 * v1);
            tb[0] = fmaf(r01, v0, -r00 * v1);
            tb[1] = fmaf(r11, v0, -r10 * v1);
            tb[2] = fmaf(r21, v0, -r20 * v1);
            tc[0] = r02 * v2; tc[1] = r12 * v2; tc[2] = r22 * v2;

            #pragma unroll
            for (int i = 0; i < 3; ++i) {
                const int n  = p_local * 3 + i;
                const int kg = kgW ^ ((n >> 1) & 3);    // swizzled slot
                Tl[0 + ks0][n][kg][jW] = (_Float16)ta[i];
                Tl[2 + ks0][n][kg][jW] = (_Float16)tb[i];
                Tl[4 + ks0][n][kg][jW] = (_Float16)tc[i];
            }
        }
    };

    // P2: MFMA over K=192, acc staged into Ys (LDS) instead of global scatter.
    auto P2 = [&]() {
        #pragma unroll
        for (int nt = 0; nt < 3; ++nt) {
            floatx4 acc = {0.f, 0.f, 0.f, 0.f};
            #pragma unroll
            for (int ks = 0; ks < 6; ++ks) {
                half8 b = *(const half8*)&Tl[ks][nt * 16 + (lane & 15)][kgR][0];
                acc = __builtin_amdgcn_mfma_f32_16x16x32_f16(afrag[ks], b, acc, 0, 0, 0);
            }
            const int n = nt * 16 + (lane & 15);
            const int pl2 = (n * 171) >> 9;      // n/3 for n < 96
            const int i2  = n - pl2 * 3;
            const int fbase = w * 16 + (lane >> 4) * 4;
            #pragma unroll
            for (int r = 0; r < 4; ++r)
                Ys[pl2 * 192 + (fbase + r) * 3 + i2] = acc[r];
        }
    };

    // Coalesced Y store: block's 12 KB slice, 3 float4 per thread.
    auto STORE_Y = [&](int it) {
        float* yb = Y + (size_t)(blockIdx.x * ITERS + it) * PB * 192;
        #pragma unroll
        for (int k = 0; k < 3; ++k) {
            const int d = (tid + 256 * k) * 4;
            floatx4 v = *(const floatx4*)&Ys[d];
            __builtin_nontemporal_store(v.x, &yb[d + 0]);
            __builtin_nontemporal_store(v.y, &yb[d + 1]);
            __builtin_nontemporal_store(v.z, &yb[d + 2]);
            __builtin_nontemporal_store(v.w, &yb[d + 3]);
        }
    };

    // ---- Pipeline: 2 barriers/iter.
    LOAD(0);
    P1();
    for (int t = 0; t < ITERS; ++t) {
        __syncthreads();                   // Tl(t) visible
        if (t + 1 < ITERS) LOAD(t + 1);    // prefetch; consumed by next P1
        P2();                              // read Tl, MFMA, stage acc -> Ys
        __syncthreads();                   // Ys visible; Tl reads done
        STORE_Y(t);                        // coalesced float4 nt stores
        if (t + 1 < ITERS) P1();           // overwrite Tl for t+1 (safe: Ys separate)
    }
}

extern "C" void kernel_launch(void* const* d_in, const int* in_sizes, int n_in,
                              void* d_out, int out_size, void* d_ws, size_t ws_size,
                              hipStream_t stream) {
    const float* X  = (const float*)d_in[0];
    const float* J  = (const float*)d_in[1];
    const float* A  = (const float*)d_in[2];
    const float* Bw = (const float*)d_in[3];
    const float* Cm = (const float*)d_in[4];
    float* Y = (float*)d_out;
    fused_mfma<<<BLOCKS, THREADS, 0, stream>>>(X, J, A, Bw, Cm, Y);
}